// Round 2
// baseline (2146.480 us; speedup 1.0000x reference)
//
#include <hip/hip_runtime.h>

#define IN_FEATURES 4096
#define IN_BLK      1024
#define BLK_R       16
#define NBLOCKS     4
#define CHUNK       32
#define NCH         8              // float4 per row per chunk
#define NITER       (IN_BLK / CHUNK)   // 32

// 256 threads = 4 waves; wave n owns diagonal block n for 64 rows (lane = row).
// x: global -> regs (depth-2 prefetch) -> XOR-swizzled LDS -> registers.
// weights: pointer laundered into VGPRs so loads stay VECTOR (global_load_dwordx4,
// uniform address -> one L1 line per request) instead of s_load -> no SGPR spill.
// No barriers: LDS regions are wave-private.
__global__ __launch_bounds__(256, 2)
void MonarchFactor_kernel(const float* __restrict__ x,
                          const float* __restrict__ w,
                          float* __restrict__ out)
{
    // 4 waves x 2 buffers x (64 rows x 8 float4) = 64 KiB
    __shared__ float4 lds[NBLOCKS][2][64 * NCH];

    const int tid  = threadIdx.x;
    const int n    = __builtin_amdgcn_readfirstlane(tid >> 6);
    const int lane = tid & 63;
    const long long row0 = (long long)blockIdx.x * 64;

    const float* xbase = x + row0 * IN_FEATURES + (long long)n * IN_BLK;

    // Launder the weight base pointer through a VGPR: the compiler can no longer
    // prove uniformity, so weight loads stay on the vector-memory path.
    unsigned long long wq = (unsigned long long)(w + (long long)n * (BLK_R * IN_BLK));
    asm("" : "+v"(wq));
    const float* wp = (const float*)wq;

    float acc[BLK_R];
#pragma unroll
    for (int r = 0; r < BLK_R; ++r) acc[r] = 0.f;

    // staging: load g covers rows [8g,8g+8); lane -> row 8g + lane/8, col lane%8.
    const int lrow = lane >> 3;
    const int lcol = lane & 7;
    const int wslot = lrow * NCH + (lcol ^ lrow);   // + g*64 ; XOR swizzle
    const float* gld = xbase + (long long)lrow * IN_FEATURES + lcol * 4;

    float4* b0 = &lds[n][0][0];
    float4* b1 = &lds[n][1][0];

    float4 Ga[8], Gb[8];

#define LOADX(T, G)                                                          \
    {                                                                        \
        _Pragma("unroll")                                                    \
        for (int g = 0; g < 8; ++g)                                          \
            G[g] = *(const float4*)(gld + (long long)(T) * CHUNK             \
                                        + (long long)(8 * g) * IN_FEATURES); \
    }

#define STOREX(G, BS)                                                        \
    {                                                                        \
        _Pragma("unroll")                                                    \
        for (int g = 0; g < 8; ++g)                                          \
            BS[g * 64 + wslot] = G[g];                                       \
    }

#define COMPUTE(T, BC)                                                      \
    {                                                                       \
        const float* wt = wp + (T) * CHUNK;                                 \
        _Pragma("unroll")                                                   \
        for (int c = 0; c < NCH; ++c) {                                     \
            const float4 xv = BC[lane * NCH + (c ^ (lane & 7))];            \
            float4 wv[BLK_R];                                               \
            _Pragma("unroll")                                               \
            for (int r = 0; r < BLK_R; ++r)                                 \
                wv[r] = *(const float4*)(wt + r * IN_BLK + c * 4);          \
            _Pragma("unroll")                                               \
            for (int r = 0; r < BLK_R; ++r) {                               \
                acc[r] = fmaf(xv.x, wv[r].x, acc[r]);                       \
                acc[r] = fmaf(xv.y, wv[r].y, acc[r]);                       \
                acc[r] = fmaf(xv.z, wv[r].z, acc[r]);                       \
                acc[r] = fmaf(xv.w, wv[r].w, acc[r]);                       \
            }                                                               \
        }                                                                   \
    }

    // prologue: tile0 -> LDS buf0; tile1 -> Ga (in flight)
    LOADX(0, Ga);
    STOREX(Ga, b0);
    LOADX(1, Ga);

    // steady state: compute t from LDS; prefetch t+2 to regs; store t+1 to LDS.
    for (int t = 0; t < NITER; t += 2) {
        COMPUTE(t, b0);
        if (t + 2 < NITER) LOADX(t + 2, Gb);
        STOREX(Ga, b1);                    // tile t+1 (always valid: NITER even)
        COMPUTE(t + 1, b1);
        if (t + 3 < NITER) LOADX(t + 3, Ga);
        if (t + 2 < NITER) STOREX(Gb, b0); // tile t+2
    }

#undef LOADX
#undef STOREX
#undef COMPUTE

    // epilogue: 16 outputs for (row0+lane, block n)
    float* obase = out + (row0 + lane) * (long long)(NBLOCKS * BLK_R) + n * BLK_R;
#pragma unroll
    for (int j = 0; j < 4; ++j) {
        float4 v = make_float4(acc[4*j+0], acc[4*j+1], acc[4*j+2], acc[4*j+3]);
        *(float4*)(obase + 4 * j) = v;
    }
}

extern "C" void kernel_launch(void* const* d_in, const int* in_sizes, int n_in,
                              void* d_out, int out_size, void* d_ws, size_t ws_size,
                              hipStream_t stream) {
    const float* x = (const float*)d_in[0];
    const float* w = (const float*)d_in[1];
    float* out = (float*)d_out;

    const int rows   = in_sizes[0] / IN_FEATURES;   // 32768
    const int blocks = rows / 64;                   // 512

    hipLaunchKernelGGL(MonarchFactor_kernel, dim3(blocks), dim3(256), 0, stream,
                       x, w, out);
}

// Round 3
// 590.627 us; speedup vs baseline: 3.6342x; 3.6342x over previous
//
#include <hip/hip_runtime.h>

#define IN_F   4096
#define IN_BLK 1024
#define BLK_R  16
#define CHUNK  32
#define NCH    8              // float4 per row per chunk
#define NITER  32             // IN_BLK / CHUNK

// 256 threads = 4 waves; wave n owns diagonal block n for the block's 64 rows.
// x:  global -> regs (depth-2) -> XOR-swizzled LDS (double buffer) -> regs.
// w:  global -> regs (depth-2) -> XOR-swizzled LDS (single buffer) -> broadcast reads.
// Lane = (rq,rg): 4 outputs (rq*4+o) x 4 rows (rg+16j) -> each LDS read feeds 16 FMAs.
// No barriers: all LDS regions are wave-private; same-wave DS ordering suffices.
__global__ __launch_bounds__(256, 2)
void MonarchFactor_kernel(const float* __restrict__ x,
                          const float* __restrict__ w,
                          float* __restrict__ out)
{
    __shared__ float4 lx[4][2][64 * NCH];    // 64 KiB  (x tiles)
    __shared__ float4 lw[4][BLK_R * NCH];    //  8 KiB  (w chunk)

    const int tid  = threadIdx.x;
    const int n    = __builtin_amdgcn_readfirstlane(tid >> 6);
    const int lane = tid & 63;
    const long long row0 = (long long)blockIdx.x * 64;

    const float* xbase = x + row0 * IN_F + n * IN_BLK;
    const float* wbase = w + n * (BLK_R * IN_BLK);

    // x staging: inst g covers rows [8g,8g+8); lane -> row 8g+(lane>>3), col lane&7.
    // LDS slot(row,c) = row*8 + (c ^ (row&7))  -- per-row XOR swizzle.
    const int lrow = lane >> 3, lcol = lane & 7;
    const int xslot = lrow * NCH + (lcol ^ lrow);              // + g*64
    const float* xg = xbase + (long long)lrow * IN_F + lcol * 4;

    // w staging: lane covers r = lane>>2, k-part = lane&3 (8 floats = 2 float4).
    // LDS slot(r,c) = r*8 + (c ^ (r>>2)).
    const int wr = lane >> 2, wkp = lane & 3;
    const float* wg = wbase + wr * IN_BLK + wkp * 8;
    const int wslot0 = wr * NCH + ((wkp * 2)     ^ (wr >> 2));
    const int wslot1 = wr * NCH + ((wkp * 2 + 1) ^ (wr >> 2));

    // compute decomposition
    const int rq = lane >> 4;        // outputs rq*4 .. rq*4+3
    const int rg = lane & 15;        // rows rg + 16j, j = 0..3

    float4* bx0 = &lx[n][0][0];
    float4* bx1 = &lx[n][1][0];
    float4* bw  = &lw[n][0];

    float acc[4][4];                 // [j][o], all indices compile-time
#pragma unroll
    for (int j = 0; j < 4; ++j)
#pragma unroll
        for (int o = 0; o < 4; ++o) acc[j][o] = 0.f;

    float4 Gxa[8], Gxb[8], Gwa[2], Gwb[2];

#define LOADX(T, G)                                                           \
    {                                                                         \
        _Pragma("unroll")                                                     \
        for (int g = 0; g < 8; ++g)                                           \
            G[g] = *(const float4*)(xg + (long long)(T) * CHUNK               \
                                       + (long long)(8 * g) * IN_F);          \
    }
#define STOREX(G, B)                                                          \
    {                                                                         \
        _Pragma("unroll")                                                     \
        for (int g = 0; g < 8; ++g) B[g * 64 + xslot] = G[g];                 \
    }
#define LOADW(T, G)                                                           \
    {                                                                         \
        G[0] = *(const float4*)(wg + (T) * CHUNK);                            \
        G[1] = *(const float4*)(wg + (T) * CHUNK + 4);                        \
    }
#define STOREW(G)                                                             \
    {                                                                         \
        bw[wslot0] = G[0];                                                    \
        bw[wslot1] = G[1];                                                    \
    }
#define COMPUTE(B)                                                            \
    {                                                                         \
        _Pragma("unroll")                                                     \
        for (int c = 0; c < NCH; ++c) {                                       \
            const int sx = c ^ (rg & 7);                                      \
            const int sw = c ^ rq;                                            \
            float4 xv[4], wv[4];                                              \
            _Pragma("unroll")                                                 \
            for (int j = 0; j < 4; ++j) xv[j] = B[(rg + 16 * j) * NCH + sx];  \
            _Pragma("unroll")                                                 \
            for (int o = 0; o < 4; ++o) wv[o] = bw[(rq * 4 + o) * NCH + sw];  \
            _Pragma("unroll")                                                 \
            for (int j = 0; j < 4; ++j)                                       \
                _Pragma("unroll")                                             \
                for (int o = 0; o < 4; ++o) {                                 \
                    acc[j][o] = fmaf(xv[j].x, wv[o].x, acc[j][o]);            \
                    acc[j][o] = fmaf(xv[j].y, wv[o].y, acc[j][o]);            \
                    acc[j][o] = fmaf(xv[j].z, wv[o].z, acc[j][o]);            \
                    acc[j][o] = fmaf(xv[j].w, wv[o].w, acc[j][o]);            \
                }                                                             \
        }                                                                     \
    }

    // prologue: tile0 -> LDS; tile1 -> regs (in flight)
    LOADX(0, Gxa); LOADW(0, Gwa);
    STOREX(Gxa, bx0); STOREW(Gwa);
    LOADX(1, Gxa); LOADW(1, Gwa);

    for (int t = 0; t < NITER; t += 2) {
        COMPUTE(bx0);                                       // tile t
        if (t + 2 < NITER) { LOADX(t + 2, Gxb); LOADW(t + 2, Gwb); }
        STOREX(Gxa, bx1); STOREW(Gwa);                      // tile t+1 (w after reads of t)
        COMPUTE(bx1);                                       // tile t+1
        if (t + 3 < NITER) { LOADX(t + 3, Gxa); LOADW(t + 3, Gwa); }
        if (t + 2 < NITER) { STOREX(Gxb, bx0); STOREW(Gwb); }   // tile t+2
    }

#undef LOADX
#undef STOREX
#undef LOADW
#undef STOREW
#undef COMPUTE

    // epilogue: lane (rq,rg) holds rows rg+16j, outputs n*16 + rq*4 + o
    float* ob = out + (row0 + rg) * 64 + n * BLK_R + rq * 4;
#pragma unroll
    for (int j = 0; j < 4; ++j) {
        float4 v = make_float4(acc[j][0], acc[j][1], acc[j][2], acc[j][3]);
        *(float4*)(ob + (long long)(16 * j) * 64) = v;
    }
}

extern "C" void kernel_launch(void* const* d_in, const int* in_sizes, int n_in,
                              void* d_out, int out_size, void* d_ws, size_t ws_size,
                              hipStream_t stream) {
    const float* x = (const float*)d_in[0];
    const float* w = (const float*)d_in[1];
    float* out = (float*)d_out;

    const int rows   = in_sizes[0] / IN_F;   // 32768
    const int blocks = rows / 64;            // 512

    hipLaunchKernelGGL(MonarchFactor_kernel, dim3(blocks), dim3(256), 0, stream,
                       x, w, out);
}

// Round 4
// 140.366 us; speedup vs baseline: 15.2920x; 4.2077x over previous
//
#include <hip/hip_runtime.h>

#define IN_F   4096
#define IN_BLK 1024
#define BLK_R  16
#define CHUNK  32
#define NCH    8               // float4 per row per chunk
#define NITER  32              // IN_BLK / CHUNK

typedef __attribute__((address_space(1))) const void g_void;
typedef __attribute__((address_space(3))) void lds_void;

// 256 threads = 4 waves; wave n owns diagonal block n for the block's 64 rows.
// x and w staged by global_load_lds (DMA, no VGPR round-trip). LDS dest is
// linear (lane*16B); the XOR bank-swizzle is applied by permuting the per-lane
// GLOBAL source address (write side) and the ds_read index (read side) with the
// same involution. Depth-2 pipeline, counted vmcnt(10), no barriers (LDS is
// wave-private; same-wave ordering only).
__global__ __launch_bounds__(256, 2)
void MonarchFactor_kernel(const float* __restrict__ x,
                          const float* __restrict__ w,
                          float* __restrict__ out)
{
    __shared__ float4 lx[4][2][64 * NCH];      // 64 KiB: x tiles
    __shared__ float4 lw[4][2][BLK_R * NCH];   // 16 KiB: w chunks

    const int tid  = threadIdx.x;
    const int n    = __builtin_amdgcn_readfirstlane(tid >> 6);
    const int lane = tid & 63;
    const long long row0 = (long long)blockIdx.x * 64;

    const float* xbase = x + row0 * IN_F + n * IN_BLK;
    const float* wbase = w + n * (BLK_R * IN_BLK);

    // pre-swizzled per-lane global sources (the write side of the XOR swizzle)
    const int l3 = lane >> 3, l7 = lane & 7, l5 = lane >> 5;
    // x inst g: slot l <- x[8g + l3][ (l7 ^ l3) ]  (float4 col)
    const float* xsrc = xbase + (long long)l3 * IN_F + ((l7 ^ l3) << 2);
    // w inst h: slot 64h+l <- w[8h + l3][ l7 ^ (2h + l5) ]
    const float* wsrc0 = wbase + l3 * IN_BLK + ((l7 ^ l5) << 2);
    const float* wsrc1 = wbase + (8 + l3) * IN_BLK + ((l7 ^ (2 + l5)) << 2);

    // compute decomposition: lane = (rq, rg) -> outputs rq*4+o, rows rg+16j
    const int rq = lane >> 4;
    const int rg = lane & 15;

    float acc[4][4];
#pragma unroll
    for (int j = 0; j < 4; ++j)
#pragma unroll
        for (int o = 0; o < 4; ++o) acc[j][o] = 0.f;

#define ISSUE(T, B)                                                            \
    {                                                                          \
        _Pragma("unroll")                                                      \
        for (int g = 0; g < 8; ++g)                                            \
            __builtin_amdgcn_global_load_lds(                                  \
                (g_void*)(xsrc + (long long)(T) * CHUNK                        \
                               + (long long)(8 * g) * IN_F),                   \
                (lds_void*)&lx[n][B][g * 64], 16, 0, 0);                       \
        __builtin_amdgcn_global_load_lds(                                      \
            (g_void*)(wsrc0 + (T) * CHUNK),                                    \
            (lds_void*)&lw[n][B][0], 16, 0, 0);                                \
        __builtin_amdgcn_global_load_lds(                                      \
            (g_void*)(wsrc1 + (T) * CHUNK),                                    \
            (lds_void*)&lw[n][B][64], 16, 0, 0);                               \
    }

#define COMPUTE(B)                                                             \
    {                                                                          \
        _Pragma("unroll")                                                      \
        for (int c = 0; c < NCH; ++c) {                                        \
            const int sx = c ^ (rg & 7);                                       \
            const int sw = c ^ rq;                                             \
            float4 xv[4], wv[4];                                               \
            _Pragma("unroll")                                                  \
            for (int j = 0; j < 4; ++j)                                        \
                xv[j] = lx[n][B][(rg + 16 * j) * NCH + sx];                    \
            _Pragma("unroll")                                                  \
            for (int o = 0; o < 4; ++o)                                        \
                wv[o] = lw[n][B][(rq * 4 + o) * NCH + sw];                     \
            _Pragma("unroll")                                                  \
            for (int j = 0; j < 4; ++j)                                        \
                _Pragma("unroll")                                              \
                for (int o = 0; o < 4; ++o) {                                  \
                    acc[j][o] = fmaf(xv[j].x, wv[o].x, acc[j][o]);             \
                    acc[j][o] = fmaf(xv[j].y, wv[o].y, acc[j][o]);             \
                    acc[j][o] = fmaf(xv[j].z, wv[o].z, acc[j][o]);             \
                    acc[j][o] = fmaf(xv[j].w, wv[o].w, acc[j][o]);             \
                }                                                              \
        }                                                                      \
    }

#define WAIT10 { asm volatile("s_waitcnt vmcnt(10)" ::: "memory");             \
                 __builtin_amdgcn_sched_barrier(0); }
#define WAIT0  { asm volatile("s_waitcnt vmcnt(0)"  ::: "memory");             \
                 __builtin_amdgcn_sched_barrier(0); }
#define SB     __builtin_amdgcn_sched_barrier(0);

    // prologue: tiles 0,1 in flight
    ISSUE(0, 0);
    ISSUE(1, 1);

    // steady state: wait tile t (10 newest ops belong to t+1), compute, refill.
    for (int t = 0; t < NITER - 2; t += 2) {
        WAIT10; COMPUTE(0); SB; ISSUE(t + 2, 0);
        WAIT10; COMPUTE(1); SB; ISSUE(t + 3, 1);
    }
    WAIT10; COMPUTE(0);      // tile 30
    WAIT0;  COMPUTE(1);      // tile 31

#undef ISSUE
#undef COMPUTE
#undef WAIT10
#undef WAIT0
#undef SB

    // epilogue: lane (rq,rg) holds rows rg+16j, outputs n*16 + rq*4 + o
    float* ob = out + (row0 + rg) * 64 + n * BLK_R + rq * 4;
#pragma unroll
    for (int j = 0; j < 4; ++j) {
        float4 v = make_float4(acc[j][0], acc[j][1], acc[j][2], acc[j][3]);
        *(float4*)(ob + (long long)(16 * j) * 64) = v;
    }
}

extern "C" void kernel_launch(void* const* d_in, const int* in_sizes, int n_in,
                              void* d_out, int out_size, void* d_ws, size_t ws_size,
                              hipStream_t stream) {
    const float* x = (const float*)d_in[0];
    const float* w = (const float*)d_in[1];
    float* out = (float*)d_out;

    const int rows   = in_sizes[0] / IN_F;   // 32768
    const int blocks = rows / 64;            // 512

    hipLaunchKernelGGL(MonarchFactor_kernel, dim3(blocks), dim3(256), 0, stream,
                       x, w, out);
}